// Round 3
// baseline (445.221 us; speedup 1.0000x reference)
//
#include <hip/hip_runtime.h>

// T=2000 tags, V=20000 videos, D=768, E_POS=E_NEG=100000
// Outputs (fp32, concat): cls_score [V,T], labels [V,T]
//
// Round 14: lane-per-edge dot phase.
// Evidence (R11/R12/R13 triangulation): gather/dot ~105us, writers ~55us
// (at write floor), ka+k2 ~20us, in-graph poison fill ~206us. The old dot
// phase was latency-bound: per edge, dependent gathers + a serial 6-step
// shuffle-reduce, sequenced over ~10 edges/wave.
// New k3l: each lane owns ONE edge and computes the full 768-dot itself.
//   - video row staged once into per-wave LDS (uniform ds_read = broadcast)
//   - each lane streams its own tag row: 96 independent 16B loads, unroll 4
//   - 4 accumulators break the FMA chain; ZERO shuffles in the dot phase
// Numerics identical to round 11 (bf16 tag x fp32 video, fp32 acc).
// Writers/ka/k2 = round 11 exactly (proven); memset dropped.

#define T_DIM 2000
#define V_DIM 20000
#define D_DIM 768
#define EPOS  100000
#define ENEG  100000
#define ETOT  (EPOS + ENEG)

#define CAP   96
#define ROW4  (T_DIM / 4)   // 500 float4 per output row

// d_ws layout (int indices):
#define WS_CURSOR 0
#define WS_PACKED 20480                       // V_DIM*CAP ints
#define WS_TAG16  (20480 + V_DIM * CAP)       // T_DIM*D_DIM ushorts

typedef float vfloat4 __attribute__((ext_vector_type(4)));

__device__ __forceinline__ ushort f2bf(float x)   // round-to-nearest-even
{
    unsigned u = __float_as_uint(x);
    u += 0x7FFFu + ((u >> 16) & 1u);
    return (ushort)(u >> 16);
}

__device__ __forceinline__ void unpack4(uint2 u, float* f)
{
    f[0] = __uint_as_float(u.x << 16);
    f[1] = __uint_as_float(u.x & 0xFFFF0000u);
    f[2] = __uint_as_float(u.y << 16);
    f[3] = __uint_as_float(u.y & 0xFFFF0000u);
}

// ---------------- KA: tag convert + cursor zero (fused) ----------------
__global__ __launch_bounds__(256) void ka_init(
    const vfloat4* __restrict__ tag_in, ushort4* __restrict__ tag16, int* ws)
{
    const int i = blockIdx.x * 256 + threadIdx.x;
    if (i < T_DIM * D_DIM / 4) {
        const vfloat4 v = __builtin_nontemporal_load(&tag_in[i]);
        ushort4 o;
        o.x = f2bf(v.x); o.y = f2bf(v.y); o.z = f2bf(v.z); o.w = f2bf(v.w);
        tag16[i] = o;
    }
    if (i < V_DIM) ws[WS_CURSOR + i] = 0;
}

// ---------------- K2: bucket edges by dst ----------------
__global__ __launch_bounds__(256) void k2_bucket(
    const int* __restrict__ pos_src,
    const int* __restrict__ pos_dst,
    const int* __restrict__ neg_src,
    const int* __restrict__ neg_dst,
    int* ws)
{
    const int e = blockIdx.x * 256 + threadIdx.x;
    if (e >= ETOT) return;
    const int src = (e < EPOS) ? pos_src[e] : neg_src[e - EPOS];
    const int dst = (e < EPOS) ? pos_dst[e] : neg_dst[e - EPOS];
    const int slot = atomicAdd(&ws[WS_CURSOR + dst], 1);
    if (slot < CAP)   // src fits in 16 bits (T=2000); bit16 = is_pos
        ws[WS_PACKED + dst * CAP + slot] = src | ((e < EPOS) ? 0x10000 : 0);
}

// ---------------- K3L: lane-per-edge dots + ballot-merge writers ----------------
__global__ __launch_bounds__(256) void k3l(
    const float*  __restrict__ h_video,
    const ushort* __restrict__ tag16,
    const int*    __restrict__ ws,
    float*        __restrict__ cls_score,
    float*        __restrict__ labels)
{
    __shared__ vfloat4 vlds[4][192];               // per-wave private video row

    const int lane = threadIdx.x & 63;
    const int w    = threadIdx.x >> 6;
    const int v    = blockIdx.x * 4 + w;
    if (v >= V_DIM) return;                        // no barriers in kernel: safe

    const int cnt  = min(ws[WS_CURSOR + v], CAP);
    const int ncnt = min(cnt, 64);                 // P(bucket>64) ~ 1e-50

    const int* pk  = ws + WS_PACKED + v * CAP;
    const int  pre = (lane < ncnt) ? pk[lane] : 0; // coalesced bucket prefetch

    const bool valid  = lane < ncnt;
    const int  my_src = valid ? (pre & 0xFFFF) : 0;  // invalid lanes -> row 0
    const int  my_j   = my_src >> 8;               // pass index (256 tags/pass)
    const bool is_pos = valid && (pre & 0x10000);

    // video row loads issued EARLY; labels writer below covers their latency
    const vfloat4* b4 = (const vfloat4*)(h_video + (size_t)v * D_DIM);
    const vfloat4 B0 = __builtin_nontemporal_load(&b4[lane]);
    const vfloat4 B1 = __builtin_nontemporal_load(&b4[lane + 64]);
    const vfloat4 B2 = __builtin_nontemporal_load(&b4[lane + 128]);

    // ---- labels writer FIRST (depends only on the bucket) ----
    vfloat4* ol = (vfloat4*)(labels + (size_t)v * T_DIM);
#pragma unroll
    for (int j = 0; j < 8; ++j) {
        const int c = j * 64 + lane;               // chunk (float4) index
        vfloat4 lab = {0.f, 0.f, 0.f, 0.f};
        unsigned long long m = __ballot(is_pos && (my_j == j));
        while (m) {                                // avg ~0.6 hits/pass
            const int k = __builtin_ctzll(m);
            m &= m - 1;
            const int src = __shfl(my_src, k, 64);
            if ((src >> 2) == c) {
                const int pos = src & 3;
                if (pos == 0)      lab.x += 1.0f;
                else if (pos == 1) lab.y += 1.0f;
                else if (pos == 2) lab.z += 1.0f;
                else               lab.w += 1.0f;
            }
        }
        if (c < ROW4)
            __builtin_nontemporal_store(lab, &ol[c]);
    }

    // ---- stage video row into per-wave LDS (no barrier needed) ----
    vlds[w][lane]       = B0;
    vlds[w][lane + 64]  = B1;
    vlds[w][lane + 128] = B2;

    // ---- dot phase: each lane streams its own tag row; zero shuffles ----
    float myscore = 0.0f;
    if (ncnt > 0) {
        const uint4* trow = (const uint4*)(tag16 + (size_t)my_src * D_DIM);
        float acc0 = 0.f, acc1 = 0.f, acc2 = 0.f, acc3 = 0.f;
#pragma unroll 4
        for (int i = 0; i < 96; ++i) {             // 96 x 16B = full row
            const uint4 t = trow[i];               // per-lane gather (L2)
            const vfloat4 v0 = vlds[w][2 * i];     // uniform addr = broadcast
            const vfloat4 v1 = vlds[w][2 * i + 1];
            uint2 lo, hi;
            lo.x = t.x; lo.y = t.y;
            hi.x = t.z; hi.y = t.w;
            float a[8];
            unpack4(lo, a);
            unpack4(hi, a + 4);
            acc0 = fmaf(a[0], v0.x, acc0);
            acc1 = fmaf(a[1], v0.y, acc1);
            acc2 = fmaf(a[2], v0.z, acc2);
            acc3 = fmaf(a[3], v0.w, acc3);
            acc0 = fmaf(a[4], v1.x, acc0);
            acc1 = fmaf(a[5], v1.y, acc1);
            acc2 = fmaf(a[6], v1.z, acc2);
            acc3 = fmaf(a[7], v1.w, acc3);
        }
        myscore = (acc0 + acc1) + (acc2 + acc3);
    }

    // ---- cls_score writer (ballot-directed merge) ----
    vfloat4* oc = (vfloat4*)(cls_score + (size_t)v * T_DIM);
#pragma unroll
    for (int j = 0; j < 8; ++j) {
        const int c = j * 64 + lane;
        vfloat4 val = {0.f, 0.f, 0.f, 0.f};
        unsigned long long m = __ballot(valid && (my_j == j));
        while (m) {                                // avg ~1.25 hits/pass
            const int k = __builtin_ctzll(m);
            m &= m - 1;
            const int src = __shfl(my_src,  k, 64);
            const float s = __shfl(myscore, k, 64);
            if ((src >> 2) == c) {
                const int pos = src & 3;
                if (pos == 0)      val.x += s;
                else if (pos == 1) val.y += s;
                else if (pos == 2) val.z += s;
                else               val.w += s;
            }
        }
        if (c < ROW4)
            __builtin_nontemporal_store(val, &oc[c]);
    }
}

extern "C" void kernel_launch(void* const* d_in, const int* in_sizes, int n_in,
                              void* d_out, int out_size, void* d_ws, size_t ws_size,
                              hipStream_t stream)
{
    const float* h_tag   = (const float*)d_in[0];
    const float* h_video = (const float*)d_in[1];
    const int*   pos_src = (const int*)d_in[2];
    const int*   pos_dst = (const int*)d_in[3];
    const int*   neg_src = (const int*)d_in[4];
    const int*   neg_dst = (const int*)d_in[5];

    float*  cls_score = (float*)d_out;                          // [V, T]
    float*  labels    = (float*)d_out + (size_t)V_DIM * T_DIM;  // [V, T]
    int*    ws        = (int*)d_ws;
    ushort* tag16     = (ushort*)(ws + WS_TAG16);

    const int n4_tag = T_DIM * D_DIM / 4;   // 384,000

    ka_init<<<(n4_tag + 255) / 256, 256, 0, stream>>>(
        (const vfloat4*)h_tag, (ushort4*)tag16, ws);

    k2_bucket<<<(ETOT + 255) / 256, 256, 0, stream>>>(
        pos_src, pos_dst, neg_src, neg_dst, ws);

    k3l<<<(V_DIM + 3) / 4, 256, 0, stream>>>(
        h_video, tag16, ws, cls_score, labels);
}

// Round 4
// 431.254 us; speedup vs baseline: 1.0324x; 1.0324x over previous
//
#include <hip/hip_runtime.h>

// T=2000 tags, V=20000 videos, D=768, E_POS=E_NEG=100000
// Outputs (fp32, concat): cls_score [V,T], labels [V,T]
//
// Round 15: parallelize the per-video edge loop ACROSS waves.
// Evidence: R11 dots ~105us vs ~10us floor -> latency chain from the
// serial quad loop (each wave: gather-wait -> reduce -> gather-wait, ~10
// edges sequentially). R14 proved divergent gathers are worse (keep
// cooperative row loads); R13 proved memset+atomic scatter ~= writer cost.
// k3q: one block per video, each of 4 waves owns one 4-edge quad (loops
// only when cnt>16, ~2.3% of videos). Same coalesced loads + dot12 +
// butterfly as R11, then per-lane atomicAdd scatter onto memset'd output.
//   memset : 320 MB zero fill (~48us at fill rate)
//   KA     : tag fp32->bf16 convert (3 MB, L2-resident) + cursor zero
//   K2     : bucket edges by dst video (fixed CAP)
//   K3Q    : wave-per-quad dots + atomic scatter (no row stores/merges)

#define T_DIM 2000
#define V_DIM 20000
#define D_DIM 768
#define EPOS  100000
#define ENEG  100000
#define ETOT  (EPOS + ENEG)

#define CAP   96

// d_ws layout (int indices):
#define WS_CURSOR 0
#define WS_PACKED 20480                       // V_DIM*CAP ints
#define WS_TAG16  (20480 + V_DIM * CAP)       // T_DIM*D_DIM ushorts

typedef float vfloat4 __attribute__((ext_vector_type(4)));

__device__ __forceinline__ ushort f2bf(float x)   // round-to-nearest-even
{
    unsigned u = __float_as_uint(x);
    u += 0x7FFFu + ((u >> 16) & 1u);
    return (ushort)(u >> 16);
}

__device__ __forceinline__ void unpack4(uint2 u, float* f)
{
    f[0] = __uint_as_float(u.x << 16);
    f[1] = __uint_as_float(u.x & 0xFFFF0000u);
    f[2] = __uint_as_float(u.y << 16);
    f[3] = __uint_as_float(u.y & 0xFFFF0000u);
}

// ---------------- KA: tag convert + cursor zero (fused) ----------------
__global__ __launch_bounds__(256) void ka_init(
    const vfloat4* __restrict__ tag_in, ushort4* __restrict__ tag16, int* ws)
{
    const int i = blockIdx.x * 256 + threadIdx.x;
    if (i < T_DIM * D_DIM / 4) {
        const vfloat4 v = __builtin_nontemporal_load(&tag_in[i]);
        ushort4 o;
        o.x = f2bf(v.x); o.y = f2bf(v.y); o.z = f2bf(v.z); o.w = f2bf(v.w);
        tag16[i] = o;
    }
    if (i < V_DIM) ws[WS_CURSOR + i] = 0;
}

// ---------------- K2: bucket edges by dst ----------------
__global__ __launch_bounds__(256) void k2_bucket(
    const int* __restrict__ pos_src,
    const int* __restrict__ pos_dst,
    const int* __restrict__ neg_src,
    const int* __restrict__ neg_dst,
    int* ws)
{
    const int e = blockIdx.x * 256 + threadIdx.x;
    if (e >= ETOT) return;
    const int src = (e < EPOS) ? pos_src[e] : neg_src[e - EPOS];
    const int dst = (e < EPOS) ? pos_dst[e] : neg_dst[e - EPOS];
    const int slot = atomicAdd(&ws[WS_CURSOR + dst], 1);
    if (slot < CAP)   // src fits in 16 bits (T=2000); bit16 = is_pos
        ws[WS_PACKED + dst * CAP + slot] = src | ((e < EPOS) ? 0x10000 : 0);
}

// ---------------- K3Q helpers ----------------
__device__ __forceinline__ void load_tag_row(
    const ushort* tag16, int src, int lane, uint2* A)
{
    const uint2* a2 = (const uint2*)(tag16 + (size_t)src * D_DIM);
    A[0] = a2[lane];
    A[1] = a2[lane + 64];
    A[2] = a2[lane + 128];
}

__device__ __forceinline__ float dot12(const uint2* A, const float* b)
{
    float a[12];
    unpack4(A[0], a + 0);
    unpack4(A[1], a + 4);
    unpack4(A[2], a + 8);
    float acc = 0.0f;
#pragma unroll
    for (int j = 0; j < 12; ++j)
        acc = fmaf(a[j], b[j], acc);
    return acc;
}

// ---------------- K3Q: wave-per-quad dots + atomic scatter ----------------
__global__ __launch_bounds__(256) void k3q(
    const float*  __restrict__ h_video,
    const ushort* __restrict__ tag16,
    const int*    __restrict__ ws,
    float*        __restrict__ cls_score,
    float*        __restrict__ labels)
{
    const int lane = threadIdx.x & 63;
    const int w    = threadIdx.x >> 6;
    const int v    = blockIdx.x;

    const int cnt = min(ws[WS_CURSOR + v], CAP);
    if (w * 4 >= cnt) return;                      // no quad for this wave

    // video row, cooperative (coalesced); plain loads -> L2 reuse across
    // the block's 4 waves (same CU/XCD).
    const vfloat4* b4 = (const vfloat4*)(h_video + (size_t)v * D_DIM);
    const vfloat4 B0 = b4[lane];
    const vfloat4 B1 = b4[lane + 64];
    const vfloat4 B2 = b4[lane + 128];
    const float b[12] = {B0.x, B0.y, B0.z, B0.w,
                         B1.x, B1.y, B1.z, B1.w,
                         B2.x, B2.y, B2.z, B2.w};

    const int* pk = ws + WS_PACKED + v * CAP;

    // wave w handles quads w, w+4, w+8, ... (one quad each for cnt<=16;
    // the ~2.3% of videos with cnt>16 loop).
    for (int q = w; q * 4 < cnt; q += 4) {
        const int base = q * 4;
        const int nval = min(cnt - base, 4);

        int pre = 0;                               // lane j<nval holds edge j
        if (lane < nval) pre = pk[base + lane];

        const int p0 = __shfl(pre, 0, 64) & 0xFFFF;
        const int p1 = __shfl(pre, 1, 64) & 0xFFFF;
        const int p2 = __shfl(pre, 2, 64) & 0xFFFF;
        const int p3 = __shfl(pre, 3, 64) & 0xFFFF;

        uint2 A0[3], A1[3], A2[3], A3[3];          // 12 loads in flight
        load_tag_row(tag16, p0, lane, A0);
        load_tag_row(tag16, p1, lane, A1);
        load_tag_row(tag16, p2, lane, A2);
        load_tag_row(tag16, p3, lane, A3);

        float acc0 = dot12(A0, b);
        float acc1 = dot12(A1, b);
        float acc2 = dot12(A2, b);
        float acc3 = dot12(A3, b);
#pragma unroll
        for (int off = 32; off >= 1; off >>= 1) {  // all lanes end with sums
            acc0 += __shfl_xor(acc0, off, 64);
            acc1 += __shfl_xor(acc1, off, 64);
            acc2 += __shfl_xor(acc2, off, 64);
            acc3 += __shfl_xor(acc3, off, 64);
        }

        // lane j scatters edge j (output pre-zeroed by memset)
        if (lane < nval) {
            float myacc = acc0;
            if (lane == 1) myacc = acc1;
            else if (lane == 2) myacc = acc2;
            else if (lane == 3) myacc = acc3;
            const int src = pre & 0xFFFF;
            atomicAdd(&cls_score[(size_t)v * T_DIM + src], myacc);
            if (pre & 0x10000)
                atomicAdd(&labels[(size_t)v * T_DIM + src], 1.0f);
        }
    }
}

extern "C" void kernel_launch(void* const* d_in, const int* in_sizes, int n_in,
                              void* d_out, int out_size, void* d_ws, size_t ws_size,
                              hipStream_t stream)
{
    const float* h_tag   = (const float*)d_in[0];
    const float* h_video = (const float*)d_in[1];
    const int*   pos_src = (const int*)d_in[2];
    const int*   pos_dst = (const int*)d_in[3];
    const int*   neg_src = (const int*)d_in[4];
    const int*   neg_dst = (const int*)d_in[5];

    float*  cls_score = (float*)d_out;                          // [V, T]
    float*  labels    = (float*)d_out + (size_t)V_DIM * T_DIM;  // [V, T]
    int*    ws        = (int*)d_ws;
    ushort* tag16     = (ushort*)(ws + WS_TAG16);

    // zero the output at fill rate; compute kernel only touches nonzeros
    hipMemsetAsync(d_out, 0, (size_t)2 * V_DIM * T_DIM * sizeof(float), stream);

    const int n4_tag = T_DIM * D_DIM / 4;   // 384,000

    ka_init<<<(n4_tag + 255) / 256, 256, 0, stream>>>(
        (const vfloat4*)h_tag, (ushort4*)tag16, ws);

    k2_bucket<<<(ETOT + 255) / 256, 256, 0, stream>>>(
        pos_src, pos_dst, neg_src, neg_dst, ws);

    k3q<<<V_DIM, 256, 0, stream>>>(
        h_video, tag16, ws, cls_score, labels);
}